// Round 1
// baseline (493.552 us; speedup 1.0000x reference)
//
#include <hip/hip_runtime.h>
#include <math.h>

#define NN 8192
#define DD 64
#define EE 64
#define NB 2
#define THRESH 0.7f
#define JT 64
#define IC 32
#define ISPLIT 4
#define ISPAN (NN / ISPLIT)

// ---------------------------------------------------------------------------
// Kernel 1: P = U @ W   (N x E) = (N x E)(E x E);  P[i,f] = sum_e U[i,e]W[e,f]
// ---------------------------------------------------------------------------
__global__ __launch_bounds__(256) void p_kernel(const float* __restrict__ U,
                                                const float* __restrict__ W,
                                                float* __restrict__ P) {
    __shared__ float Wl[EE * EE];
    const int t = threadIdx.x;
#pragma unroll
    for (int k = 0; k < 16; ++k) Wl[t + 256 * k] = W[t + 256 * k];
    __syncthreads();
    const int i = blockIdx.x * 4 + (t >> 6);
    const int f = t & 63;
    const float* Urow = U + i * EE;
    float acc = 0.f;
#pragma unroll
    for (int e = 0; e < EE; ++e) acc += Urow[e] * Wl[e * 64 + f];
    P[i * EE + f] = acc;
}

// ---------------------------------------------------------------------------
// Kernel 2: es[b,i,:] = relu(prof[b,i]-thr) * state[b,i,:];  out = state
// ---------------------------------------------------------------------------
__global__ __launch_bounds__(256) void es_init_kernel(const float* __restrict__ S,
                                                      const float* __restrict__ prof,
                                                      float* __restrict__ es,
                                                      float* __restrict__ out) {
    const int q = blockIdx.x * 256 + threadIdx.x;  // float4 index over B*N*D/4
    const float4 s = ((const float4*)S)[q];
    const int row = q >> 4;  // D/4 = 16 float4 per (b,i) row
    float g = prof[row] - THRESH;
    g = fmaxf(g, 0.f);
    ((float4*)out)[q] = s;
    float4 e;
    e.x = s.x * g; e.y = s.y * g; e.z = s.z * g; e.w = s.w * g;
    ((float4*)es)[q] = e;
}

// ---------------------------------------------------------------------------
// Kernel 3: fused  w = sigmoid(P U^T + b) (masked diag); out += w^T es  (B=2)
// grid = (N/JT, ISPLIT); block = 256
// ---------------------------------------------------------------------------
__global__ __launch_bounds__(256, 3) void transfer_kernel(const float* __restrict__ U,
                                                          const float* __restrict__ P,
                                                          const float* __restrict__ es,
                                                          const float* __restrict__ bias_p,
                                                          float* __restrict__ out) {
    // strides padded: 68 (mult of 4, row-rotates banks) / 34 (even, rotates banks)
    __shared__ float UT[EE][68];        // U tile transposed  [e][j]   17.0 KB
    __shared__ float PT[EE][34];        // P chunk transposed [e][i]    8.5 KB
    __shared__ float WSC[IC][68];       // masked sigmoid scores [i][j] 8.5 KB
    __shared__ float ESL[NB * IC * DD]; // gated sources [b][i][d]     16.0 KB

    const int t = threadIdx.x;
    const int j0 = blockIdx.x * JT;
    const int i_start = blockIdx.y * ISPAN;
    const float bias = bias_p[0];

    // stage U tile, transposed (coalesced global read; LDS write 2-way = free)
#pragma unroll
    for (int k = 0; k < 16; ++k) {
        int m = t + 256 * k;  // 4096 = 64j x 64e
        int j = m >> 6, e = m & 63;
        UT[e][j] = U[(j0 + j) * EE + e];
    }

    const int jg = t & 15;   // j-group (both phases)
    const int ig = t >> 4;   // i-group in phase A, d-group in phase B

    float acc[NB][4][4];
#pragma unroll
    for (int b = 0; b < NB; ++b)
#pragma unroll
        for (int r = 0; r < 4; ++r)
#pragma unroll
            for (int c = 0; c < 4; ++c) acc[b][r][c] = 0.f;

    for (int chunk = 0; chunk < ISPAN / IC; ++chunk) {
        const int i0 = i_start + chunk * IC;
        __syncthreads();  // protect LDS from previous iteration's readers

        // stage P chunk transposed
#pragma unroll
        for (int k = 0; k < 8; ++k) {
            int m = t + 256 * k;  // 2048 = 32i x 64e
            int i = m >> 6, e = m & 63;
            PT[e][i] = P[(i0 + i) * EE + e];
        }
        // stage gated sources for both batches (contiguous copy)
#pragma unroll
        for (int k = 0; k < 16; ++k) {
            int m = t + 256 * k;  // 4096 = 2b x 32i x 64d
            int b = m >> 11, i = (m >> 6) & 31, d = m & 63;
            ESL[m] = es[((b * NN) + i0 + i) * DD + d];
        }
        __syncthreads();

        // ---- phase A: 32i x 64j score tile; 2i x 4j micro-tile per thread ----
        float sc[2][4];
#pragma unroll
        for (int r = 0; r < 2; ++r)
#pragma unroll
            for (int c = 0; c < 4; ++c) sc[r][c] = 0.f;
#pragma unroll 8
        for (int e = 0; e < EE; ++e) {
            const float2 p = *(const float2*)&PT[e][2 * ig];  // 8B aligned (34e even)
            const float4 u = *(const float4*)&UT[e][4 * jg];  // 16B aligned
            sc[0][0] += p.x * u.x; sc[0][1] += p.x * u.y;
            sc[0][2] += p.x * u.z; sc[0][3] += p.x * u.w;
            sc[1][0] += p.y * u.x; sc[1][1] += p.y * u.y;
            sc[1][2] += p.y * u.z; sc[1][3] += p.y * u.w;
        }
#pragma unroll
        for (int r = 0; r < 2; ++r) {
            const int gi = i0 + 2 * ig + r;
            float4 wv;
            float* wp = &wv.x;
#pragma unroll
            for (int c = 0; c < 4; ++c) {
                const int gj = j0 + 4 * jg + c;
                const float v = 1.f / (1.f + __expf(-(sc[r][c] + bias)));
                wp[c] = (gi == gj) ? 0.f : v;  // zero self-transfer
            }
            *(float4*)&WSC[2 * ig + r][4 * jg] = wv;
        }
        __syncthreads();

        // ---- phase B: out[j,d] += sum_i w[i,j] * es[b,i,d]; 4j x 4d x 2b ----
#pragma unroll 8
        for (int i = 0; i < IC; ++i) {
            const float4 wv = *(const float4*)&WSC[i][4 * jg];
            const float4 ea = *(const float4*)&ESL[i * DD + 4 * ig];
            const float4 eb = *(const float4*)&ESL[IC * DD + i * DD + 4 * ig];
            const float wr[4] = {wv.x, wv.y, wv.z, wv.w};
            const float ca[4] = {ea.x, ea.y, ea.z, ea.w};
            const float cb[4] = {eb.x, eb.y, eb.z, eb.w};
#pragma unroll
            for (int r = 0; r < 4; ++r)
#pragma unroll
                for (int c = 0; c < 4; ++c) {
                    acc[0][r][c] += wr[r] * ca[c];
                    acc[1][r][c] += wr[r] * cb[c];
                }
        }
    }

    // epilogue: partial-sum across ISPLIT via device-scope atomics
#pragma unroll
    for (int r = 0; r < 4; ++r) {
        const int j = j0 + 4 * jg + r;
#pragma unroll
        for (int c = 0; c < 4; ++c) {
            atomicAdd(&out[j * DD + 4 * ig + c], acc[0][r][c]);
            atomicAdd(&out[(NN + j) * DD + 4 * ig + c], acc[1][r][c]);
        }
    }
}

// ---------------------------------------------------------------------------
extern "C" void kernel_launch(void* const* d_in, const int* in_sizes, int n_in,
                              void* d_out, int out_size, void* d_ws, size_t ws_size,
                              hipStream_t stream) {
    const float* states = (const float*)d_in[0];  // [B,N,D]
    const float* prof   = (const float*)d_in[1];  // [B,N]
    const float* emb    = (const float*)d_in[2];  // [N,E]
    const float* W      = (const float*)d_in[3];  // [1,E,E]
    const float* bias   = (const float*)d_in[4];  // [1]
    float* out = (float*)d_out;

    float* P  = (float*)d_ws;        // N*E floats   (2 MB)
    float* es = P + NN * EE;         // B*N*D floats (4 MB)

    p_kernel<<<NN / 4, 256, 0, stream>>>(emb, W, P);
    es_init_kernel<<<(NB * NN * DD / 4) / 256, 256, 0, stream>>>(states, prof, es, out);
    transfer_kernel<<<dim3(NN / JT, ISPLIT), 256, 0, stream>>>(emb, P, es, bias, out);
}

// Round 2
// 161.032 us; speedup vs baseline: 3.0649x; 3.0649x over previous
//
#include <hip/hip_runtime.h>
#include <math.h>

#define NN 8192
#define DD 64
#define EE 64
#define NB 2
#define THRESH 0.7f
#define JT 64
#define IC 64
#define ISPLIT 4
#define ISPAN (NN / ISPLIT)

typedef __attribute__((ext_vector_type(8))) short bf16x8;
typedef __attribute__((ext_vector_type(4))) short bf16x4;
typedef __attribute__((ext_vector_type(4))) float f32x4;

static __device__ __forceinline__ short f2bf(float x) {
    unsigned u = __float_as_uint(x);
    unsigned r = (u + 0x7fffu + ((u >> 16) & 1u)) >> 16;
    return (short)r;
}

// ---------------------------------------------------------------------------
// Kernel 1: P = U @ W (fp32 math) -> P_bf (bf16); also U -> U_bf (bf16)
// ---------------------------------------------------------------------------
__global__ __launch_bounds__(256) void p_kernel(const float* __restrict__ U,
                                                const float* __restrict__ W,
                                                short* __restrict__ P_bf,
                                                short* __restrict__ U_bf) {
    __shared__ float Wl[EE * EE];
    const int t = threadIdx.x;
#pragma unroll
    for (int k = 0; k < 16; ++k) Wl[t + 256 * k] = W[t + 256 * k];
    __syncthreads();
    const int i = blockIdx.x * 4 + (t >> 6);
    const int f = t & 63;
    const float* Urow = U + i * EE;
    float acc = 0.f;
#pragma unroll
    for (int e = 0; e < EE; ++e) acc += Urow[e] * Wl[e * 64 + f];
    P_bf[i * EE + f] = f2bf(acc);
    U_bf[i * EE + f] = f2bf(Urow[f]);
}

// ---------------------------------------------------------------------------
// Kernel 2: es_t[b*64+d][i] = bf16(relu(prof[b,i]-thr) * state[b,i,d]) ;
//           out = state (init).  Transpose via LDS for coalesced stores.
// grid = B*N/64 blocks of 256
// ---------------------------------------------------------------------------
__global__ __launch_bounds__(256) void es_init_kernel(const float* __restrict__ S,
                                                      const float* __restrict__ prof,
                                                      short* __restrict__ es_t,
                                                      float* __restrict__ out) {
    __shared__ float tr[64][65];
    __shared__ float gl[64];
    const int t = threadIdx.x;
    const int b = blockIdx.x >> 7;
    const int i0 = (blockIdx.x & 127) * 64;

    if (t < 64) gl[t] = fmaxf(prof[b * NN + i0 + t] - THRESH, 0.f);
#pragma unroll
    for (int k = 0; k < 4; ++k) {
        int idx = k * 256 + t;        // 1024 float4s = 64 i x 16
        int i = idx >> 4, c4 = idx & 15;
        const float4 s = ((const float4*)S)[(b * NN + i0 + i) * 16 + c4];
        ((float4*)out)[(b * NN + i0 + i) * 16 + c4] = s;
        tr[c4 * 4 + 0][i] = s.x;
        tr[c4 * 4 + 1][i] = s.y;
        tr[c4 * 4 + 2][i] = s.z;
        tr[c4 * 4 + 3][i] = s.w;
    }
    __syncthreads();
    const int d = t >> 2;
    const int sg = (t & 3) * 16;
#pragma unroll
    for (int h = 0; h < 2; ++h) {
        bf16x8 v;
#pragma unroll
        for (int e = 0; e < 8; ++e) {
            int ii = sg + h * 8 + e;
            v[e] = f2bf(tr[d][ii] * gl[ii]);
        }
        *(bf16x8*)(es_t + (b * 64 + d) * NN + i0 + sg + h * 8) = v;
    }
}

// ---------------------------------------------------------------------------
// Kernel 3: fused scores->sigmoid->contraction, all MFMA bf16.
// grid = (N/JT, ISPLIT), 256 threads (4 waves).
// phase A: S[64i x 64j] = P U^T   (wave w: i-rows 16w..16w+16)
// phase B: out[64j x 64d x 2b] += T^T es (wave w: (b,dt) combos 2w,2w+1)
// ---------------------------------------------------------------------------
__global__ __launch_bounds__(256, 2) void transfer_kernel(const short* __restrict__ P_bf,
                                                          const short* __restrict__ U_bf,
                                                          const short* __restrict__ es_t,
                                                          const float* __restrict__ bias_p,
                                                          float* __restrict__ out) {
    // padded stride 72 shorts = 144B: rows stay 16B-aligned, banks rotate by 4
    __shared__ __align__(16) short ES[NB * 64 * 72];  // [b*64+d][72]  18 KB
    __shared__ __align__(16) short TT[64 * 72];       // [j][72]        9 KB

    const int t = threadIdx.x;
    const int w = t >> 6;
    const int lane = t & 63;
    const int q = lane >> 4;
    const int ln = lane & 15;
    const int j0 = blockIdx.x * JT;
    const int i_base = blockIdx.y * ISPAN;
    const float bias = bias_p[0];

    // U B-fragments: resident in registers for the whole kernel.
    // B[k=e][n=j]: lane ln = j, quad covers k. 4 j-tiles x 2 k-steps.
    bf16x8 uf[4][2];
#pragma unroll
    for (int jt = 0; jt < 4; ++jt)
#pragma unroll
        for (int ks = 0; ks < 2; ++ks)
            uf[jt][ks] = *(const bf16x8*)(U_bf + (j0 + jt * 16 + ln) * EE + ks * 32 + q * 8);

    f32x4 acc[4][2];  // [j-tile][combo]
#pragma unroll
    for (int jm = 0; jm < 4; ++jm)
#pragma unroll
        for (int c = 0; c < 2; ++c) acc[jm][c] = (f32x4){0.f, 0.f, 0.f, 0.f};

    const f32x4 zero = (f32x4){0.f, 0.f, 0.f, 0.f};

    for (int chunk = 0; chunk < ISPAN / IC; ++chunk) {
        const int i0 = i_base + chunk * IC;
        __syncthreads();  // prev phase B done: safe to overwrite ES and TT

        // stage es chunk: 128 rows x 64 bf16 (8 x 16B segs) = 1024 units
#pragma unroll
        for (int k = 0; k < 4; ++k) {
            int idx = k * 256 + t;
            int row = idx >> 3, seg = idx & 7;
            *(bf16x8*)(ES + row * 72 + seg * 8) =
                *(const bf16x8*)(es_t + row * NN + i0 + seg * 8);
        }

        // P A-fragments direct from global (L2-resident)
        bf16x8 pf[2];
#pragma unroll
        for (int ks = 0; ks < 2; ++ks)
            pf[ks] = *(const bf16x8*)(P_bf + (i0 + w * 16 + ln) * EE + ks * 32 + q * 8);

        // ---- phase A: scores + sigmoid + masked, write T^T to LDS ----
#pragma unroll
        for (int jt = 0; jt < 4; ++jt) {
            f32x4 s = __builtin_amdgcn_mfma_f32_16x16x32_bf16(pf[0], uf[jt][0], zero, 0, 0, 0);
            s = __builtin_amdgcn_mfma_f32_16x16x32_bf16(pf[1], uf[jt][1], s, 0, 0, 0);
            // lane holds S[i = i0+16w+q*4+r][j = j0+jt*16+ln]
            const int gi0 = i0 + w * 16 + q * 4;
            const int gj = j0 + jt * 16 + ln;
            bf16x4 tv;
#pragma unroll
            for (int r = 0; r < 4; ++r) {
                float x = s[r] + bias;
                float T = __fdividef(1.f, 1.f + __expf(-x));
                if (gi0 + r == gj) T = 0.f;
                tv[r] = f2bf(T);
            }
            *(bf16x4*)(TT + (jt * 16 + ln) * 72 + w * 16 + q * 4) = tv;
        }
        __syncthreads();  // ES staged + TT written

        // ---- phase B: out[j][d] += T^T[j][i] * es[i][d] ----
        // wave w handles combos g = 2w, 2w+1: b = g>>2, dt = g&3
        bf16x8 bfr[2][2];
#pragma unroll
        for (int c = 0; c < 2; ++c) {
            int g = w * 2 + c;
            int row = (g >> 2) * 64 + (g & 3) * 16 + ln;  // b*64 + dt*16 + d-in-16
#pragma unroll
            for (int ks = 0; ks < 2; ++ks)
                bfr[c][ks] = *(const bf16x8*)(ES + row * 72 + ks * 32 + q * 8);
        }
#pragma unroll
        for (int jm = 0; jm < 4; ++jm) {
#pragma unroll
            for (int ks = 0; ks < 2; ++ks) {
                bf16x8 af = *(const bf16x8*)(TT + (jm * 16 + ln) * 72 + ks * 32 + q * 8);
                acc[jm][0] = __builtin_amdgcn_mfma_f32_16x16x32_bf16(af, bfr[0][ks], acc[jm][0], 0, 0, 0);
                acc[jm][1] = __builtin_amdgcn_mfma_f32_16x16x32_bf16(af, bfr[1][ks], acc[jm][1], 0, 0, 0);
            }
        }
    }

    // epilogue: lane holds out[b][j = j0+jm*16+q*4+r][d = dt*16+ln]
#pragma unroll
    for (int jm = 0; jm < 4; ++jm)
#pragma unroll
        for (int c = 0; c < 2; ++c) {
            int g = w * 2 + c;
            int bb = g >> 2, dt = g & 3;
            int j = j0 + jm * 16 + q * 4;
#pragma unroll
            for (int r = 0; r < 4; ++r)
                atomicAdd(out + (bb * NN + j + r) * DD + dt * 16 + ln, acc[jm][c][r]);
        }
}

// ---------------------------------------------------------------------------
extern "C" void kernel_launch(void* const* d_in, const int* in_sizes, int n_in,
                              void* d_out, int out_size, void* d_ws, size_t ws_size,
                              hipStream_t stream) {
    const float* states = (const float*)d_in[0];  // [B,N,D]
    const float* prof   = (const float*)d_in[1];  // [B,N]
    const float* emb    = (const float*)d_in[2];  // [N,E]
    const float* W      = (const float*)d_in[3];  // [1,E,E]
    const float* bias   = (const float*)d_in[4];  // [1]
    float* out = (float*)d_out;

    short* P_bf = (short*)d_ws;          // N*E bf16 (1 MB)
    short* U_bf = P_bf + NN * EE;        // N*E bf16 (1 MB)
    short* es_t = U_bf + NN * EE;        // B*64 x N bf16 (2 MB)

    p_kernel<<<NN / 4, 256, 0, stream>>>(emb, W, P_bf, U_bf);
    es_init_kernel<<<NB * NN / 64, 256, 0, stream>>>(states, prof, es_t, out);
    transfer_kernel<<<dim3(NN / JT, ISPLIT), 256, 0, stream>>>(P_bf, U_bf, es_t, bias, out);
}

// Round 4
// 136.009 us; speedup vs baseline: 3.6288x; 1.1840x over previous
//
#include <hip/hip_runtime.h>
#include <math.h>

#define NN 8192
#define DD 64
#define EE 64
#define NB 2
#define THRESH 0.7f
#define JT 64
#define IC 64
#define ISPLIT 8
#define ISPAN (NN / ISPLIT)
#define LOG2E 1.4426950408889634f

typedef __attribute__((ext_vector_type(8))) short bf16x8;
typedef __attribute__((ext_vector_type(4))) float f32x4;

static __device__ __forceinline__ short f2bf(float x) {  // RNE
    unsigned u = __float_as_uint(x);
    unsigned r = (u + 0x7fffu + ((u >> 16) & 1u)) >> 16;
    return (short)r;
}
// pack two fp32 -> two bf16 (truncation) in one v_perm
static __device__ __forceinline__ unsigned pack_bf_trunc(float lo, float hi) {
    return __builtin_amdgcn_perm(__float_as_uint(hi), __float_as_uint(lo), 0x07060302u);
}

// ---------------------------------------------------------------------------
// Prep kernel (one launch): blocks [0,512): P = U@W -> bf16, U -> bf16.
//                           blocks [512,768): es_t transpose + out = state.
// ---------------------------------------------------------------------------
__global__ __launch_bounds__(256) void prep_kernel(const float* __restrict__ U,
                                                   const float* __restrict__ W,
                                                   const float* __restrict__ S,
                                                   const float* __restrict__ prof,
                                                   short* __restrict__ P_bf,
                                                   short* __restrict__ U_bf,
                                                   short* __restrict__ es_t,
                                                   float* __restrict__ out) {
    __shared__ float Wl[EE * EE];   // 16 KB
    __shared__ float Ul[16 * EE];   //  4 KB
    __shared__ float tr[64][65];    // 16.25 KB
    __shared__ float gl[64];
    const int t = threadIdx.x;

    if (blockIdx.x < 512) {
        const int r0 = blockIdx.x * 16;
#pragma unroll
        for (int k = 0; k < 4; ++k)
            ((float4*)Wl)[k * 256 + t] = ((const float4*)W)[k * 256 + t];
        ((float4*)Ul)[t] = ((const float4*)U)[r0 * 16 + t];
        __syncthreads();
        const int row = t >> 4;
        const int fq = t & 15;
        const float* ur = Ul + row * EE;
        float4 acc = {0.f, 0.f, 0.f, 0.f};
#pragma unroll
        for (int e = 0; e < EE; ++e) {
            const float4 w4 = ((const float4*)Wl)[e * 16 + fq];
            const float u = ur[e];
            acc.x += u * w4.x; acc.y += u * w4.y;
            acc.z += u * w4.z; acc.w += u * w4.w;
        }
        short4 pv = {f2bf(acc.x), f2bf(acc.y), f2bf(acc.z), f2bf(acc.w)};
        *(short4*)(P_bf + (r0 + row) * EE + fq * 4) = pv;
        const float4 uv = ((const float4*)ur)[fq];
        short4 ub = {f2bf(uv.x), f2bf(uv.y), f2bf(uv.z), f2bf(uv.w)};
        *(short4*)(U_bf + (r0 + row) * EE + fq * 4) = ub;
    } else {
        const int bi = blockIdx.x - 512;
        const int b = bi >> 7;
        const int i0 = (bi & 127) * 64;
        if (t < 64) gl[t] = fmaxf(prof[b * NN + i0 + t] - THRESH, 0.f);
#pragma unroll
        for (int k = 0; k < 4; ++k) {
            int idx = k * 256 + t;
            int i = idx >> 4, c4 = idx & 15;
            const float4 s = ((const float4*)S)[(b * NN + i0 + i) * 16 + c4];
            ((float4*)out)[(b * NN + i0 + i) * 16 + c4] = s;
            tr[c4 * 4 + 0][i] = s.x;
            tr[c4 * 4 + 1][i] = s.y;
            tr[c4 * 4 + 2][i] = s.z;
            tr[c4 * 4 + 3][i] = s.w;
        }
        __syncthreads();
        const int d = t >> 2;
        const int sg = (t & 3) * 16;
#pragma unroll
        for (int h = 0; h < 2; ++h) {
            bf16x8 v;
#pragma unroll
            for (int e = 0; e < 8; ++e) {
                int ii = sg + h * 8 + e;
                v[e] = f2bf(tr[d][ii] * gl[ii]);
            }
            *(bf16x8*)(es_t + (b * 64 + d) * NN + i0 + sg + h * 8) = v;
        }
    }
}

// ---------------------------------------------------------------------------
// Transfer kernel: grid (N/JT, ISPLIT), 256 threads.
// Phase A: S = P U^T (MFMA) -> sigmoid -> T written to LDS in A-fragment order.
// Phase B: out += T^T es via MFMA; es/P fragments direct from L2.
// ---------------------------------------------------------------------------
__global__ __launch_bounds__(256, 4) void transfer_kernel(const short* __restrict__ P_bf,
                                                          const short* __restrict__ U_bf,
                                                          const short* __restrict__ es_t,
                                                          const float* __restrict__ bias_p,
                                                          float* __restrict__ out) {
    // T in MFMA-A fragment order: [jt*2+ks][lane][e(8 shorts)] = 8 KB
    __shared__ __align__(16) short TT[8 * 64 * 8];

    const int t = threadIdx.x;
    const int w = t >> 6;
    const int lane = t & 63;
    const int q = lane >> 4;
    const int ln = lane & 15;
    const int j0 = blockIdx.x * JT;
    const int i_base = blockIdx.y * ISPAN;
    const float nb = -bias_p[0] * LOG2E;  // exp term: exp2(s*-LOG2E + nb)

    // U B-fragments resident in registers for the whole kernel
    bf16x8 uf[4][2];
#pragma unroll
    for (int jt = 0; jt < 4; ++jt)
#pragma unroll
        for (int ks = 0; ks < 2; ++ks)
            uf[jt][ks] = *(const bf16x8*)(U_bf + (j0 + jt * 16 + ln) * EE + ks * 32 + q * 8);

    f32x4 acc[4][2];
#pragma unroll
    for (int jm = 0; jm < 4; ++jm)
#pragma unroll
        for (int c = 0; c < 2; ++c) acc[jm][c] = (f32x4){0.f, 0.f, 0.f, 0.f};
    const f32x4 zero = (f32x4){0.f, 0.f, 0.f, 0.f};

    // producer TT slot: i_local = 16w+4q+r -> ks=(w>>1), q'=(2w+(q>>1))&3, e0=(q&1)*4
    // ttw_off includes ks_w*128; tile stride is 256 uint2 (applied at write site)
    const int ks_w = w >> 1;
    const int qp = (2 * w + (q >> 1)) & 3;
    const int e0 = (q & 1) * 4;
    const int ttw_off = (ks_w * 64 + qp * 16 + ln) * 2 + (e0 >> 2);  // uint2 units

    for (int chunk = 0; chunk < ISPAN / IC; ++chunk) {
        const int i0 = i_base + chunk * IC;
        const bool diag = (i0 == j0);

        // issue global fragment loads early (L2-resident; hide latency over phase A)
        bf16x8 pf[2];
#pragma unroll
        for (int ks = 0; ks < 2; ++ks)
            pf[ks] = *(const bf16x8*)(P_bf + (i0 + w * 16 + ln) * EE + ks * 32 + q * 8);
        bf16x8 bfr[2][2];
#pragma unroll
        for (int c = 0; c < 2; ++c) {
            const int g = w * 2 + c;
            const short* er = es_t + (((g >> 2) * 64) + (g & 3) * 16 + ln) * NN + i0;
#pragma unroll
            for (int ks = 0; ks < 2; ++ks)
                bfr[c][ks] = *(const bf16x8*)(er + ks * 32 + q * 8);
        }

        __syncthreads();  // TT from previous chunk fully consumed

        // ---- phase A ----
#pragma unroll
        for (int jt = 0; jt < 4; ++jt) {
            f32x4 s = __builtin_amdgcn_mfma_f32_16x16x32_bf16(pf[0], uf[jt][0], zero, 0, 0, 0);
            s = __builtin_amdgcn_mfma_f32_16x16x32_bf16(pf[1], uf[jt][1], s, 0, 0, 0);
            float T[4];
#pragma unroll
            for (int r = 0; r < 4; ++r)
                T[r] = __builtin_amdgcn_rcpf(
                    1.f + __builtin_amdgcn_exp2f(fmaf(s[r], -LOG2E, nb)));
            if (diag && jt == w) {  // wave-uniform-ish: 1 of 16 chunks per block
                const int rr = ln - 4 * q;
                if (rr >= 0 && rr < 4) T[rr] = 0.f;
            }
            uint2 pk;
            pk.x = pack_bf_trunc(T[0], T[1]);
            pk.y = pack_bf_trunc(T[2], T[3]);
            ((uint2*)TT)[jt * 256 + ttw_off] = pk;  // FIX: tile stride 256, was 128
        }
        __syncthreads();  // TT complete

        // ---- phase B ----
#pragma unroll
        for (int jm = 0; jm < 4; ++jm) {
#pragma unroll
            for (int ks = 0; ks < 2; ++ks) {
                const bf16x8 af = *(const bf16x8*)(TT + ((jm * 2 + ks) * 64 + lane) * 8);
                acc[jm][0] = __builtin_amdgcn_mfma_f32_16x16x32_bf16(af, bfr[0][ks], acc[jm][0], 0, 0, 0);
                acc[jm][1] = __builtin_amdgcn_mfma_f32_16x16x32_bf16(af, bfr[1][ks], acc[jm][1], 0, 0, 0);
            }
        }
    }

    // epilogue: lane holds out[b][j0+jm*16+q*4+r][dt*16+ln]
#pragma unroll
    for (int jm = 0; jm < 4; ++jm)
#pragma unroll
        for (int c = 0; c < 2; ++c) {
            const int g = w * 2 + c;
            const int bb = g >> 2, dt = g & 3;
            const int j = j0 + jm * 16 + q * 4;
#pragma unroll
            for (int r = 0; r < 4; ++r)
                atomicAdd(out + (bb * NN + j + r) * DD + dt * 16 + ln, acc[jm][c][r]);
        }
}

// ---------------------------------------------------------------------------
extern "C" void kernel_launch(void* const* d_in, const int* in_sizes, int n_in,
                              void* d_out, int out_size, void* d_ws, size_t ws_size,
                              hipStream_t stream) {
    const float* states = (const float*)d_in[0];  // [B,N,D]
    const float* prof   = (const float*)d_in[1];  // [B,N]
    const float* emb    = (const float*)d_in[2];  // [N,E]
    const float* W      = (const float*)d_in[3];  // [1,E,E]
    const float* bias   = (const float*)d_in[4];  // [1]
    float* out = (float*)d_out;

    short* P_bf = (short*)d_ws;          // 1 MB
    short* U_bf = P_bf + NN * EE;        // 1 MB
    short* es_t = U_bf + NN * EE;        // 2 MB

    prep_kernel<<<768, 256, 0, stream>>>(emb, W, states, prof, P_bf, U_bf, es_t, out);
    transfer_kernel<<<dim3(NN / JT, ISPLIT), 256, 0, stream>>>(P_bf, U_bf, es_t, bias, out);
}

// Round 6
// 130.516 us; speedup vs baseline: 3.7815x; 1.0421x over previous
//
#include <hip/hip_runtime.h>
#include <math.h>

#define NN 8192
#define DD 64
#define EE 64
#define NB 2
#define THRESH 0.7f
#define JT 64
#define IC 64
#define ISPLIT 8
#define ISPAN (NN / ISPLIT)
#define LOG2E 1.4426950408889634f

typedef __attribute__((ext_vector_type(8))) short bf16x8;
typedef __attribute__((ext_vector_type(4))) float f32x4;
typedef __fp16 half2v __attribute__((ext_vector_type(2)));

static __device__ __forceinline__ short f2bf(float x) {  // RNE
    unsigned u = __float_as_uint(x);
    unsigned r = (u + 0x7fffu + ((u >> 16) & 1u)) >> 16;
    return (short)r;
}
// pack two fp32 -> two bf16 (truncation) in one v_perm
static __device__ __forceinline__ unsigned pack_bf_trunc(float lo, float hi) {
    return __builtin_amdgcn_perm(__float_as_uint(hi), __float_as_uint(lo), 0x07060302u);
}
// pack two fp32 -> packed fp16 pair (one v_cvt_pkrtz_f16_f32)
static __device__ __forceinline__ unsigned pk_f16(float a, float b) {
    half2v h = __builtin_amdgcn_cvt_pkrtz(a, b);
    return __builtin_bit_cast(unsigned, h);
}
static __device__ __forceinline__ float f16lo(unsigned u) {
    half2v h = __builtin_bit_cast(half2v, u);
    return (float)h[0];
}
static __device__ __forceinline__ float f16hi(unsigned u) {
    half2v h = __builtin_bit_cast(half2v, u);
    return (float)h[1];
}

// ---------------------------------------------------------------------------
// Prep: blocks [0,512): P = U@W -> bf16, U -> bf16.
//       blocks [512,640): es_t[b*64+d][i] transpose, CONTIGUOUS 256B stores.
// ---------------------------------------------------------------------------
__global__ __launch_bounds__(256) void prep_kernel(const float* __restrict__ U,
                                                   const float* __restrict__ W,
                                                   const float* __restrict__ S,
                                                   const float* __restrict__ prof,
                                                   short* __restrict__ P_bf,
                                                   short* __restrict__ U_bf,
                                                   short* __restrict__ es_t) {
    // manual union: GEMM branch uses [0,4096)=Wl, [4096,5120)=Ul
    //               es branch uses [0,8448)=tr(64x132), [8448,8576)=gl
    __shared__ float smem[64 * 132 + 128];  // 34.3 KB
    const int t = threadIdx.x;

    if (blockIdx.x < 512) {
        float* Wl = smem;
        float* Ul = smem + 4096;
        const int r0 = blockIdx.x * 16;
#pragma unroll
        for (int k = 0; k < 4; ++k)
            ((float4*)Wl)[k * 256 + t] = ((const float4*)W)[k * 256 + t];
        ((float4*)Ul)[t] = ((const float4*)U)[r0 * 16 + t];
        __syncthreads();
        const int row = t >> 4;
        const int fq = t & 15;
        const float* ur = Ul + row * EE;
        float4 acc = {0.f, 0.f, 0.f, 0.f};
#pragma unroll
        for (int e = 0; e < EE; ++e) {
            const float4 w4 = ((const float4*)Wl)[e * 16 + fq];
            const float u = ur[e];
            acc.x += u * w4.x; acc.y += u * w4.y;
            acc.z += u * w4.z; acc.w += u * w4.w;
        }
        short4 pv = {f2bf(acc.x), f2bf(acc.y), f2bf(acc.z), f2bf(acc.w)};
        *(short4*)(P_bf + (r0 + row) * EE + fq * 4) = pv;
        const float4 uv = ((const float4*)ur)[fq];
        short4 ub = {f2bf(uv.x), f2bf(uv.y), f2bf(uv.z), f2bf(uv.w)};
        *(short4*)(U_bf + (r0 + row) * EE + fq * 4) = ub;
    } else {
        float* tr = smem;           // [64][132], stride 132 (528B, 16B-aligned)
        float* gl = smem + 8448;    // [128]
        const int bi = blockIdx.x - 512;  // 0..127
        const int b = bi >> 6;
        const int i0 = (bi & 63) * 128;
        if (t < 128) gl[t] = fmaxf(prof[b * NN + i0 + t] - THRESH, 0.f);
        __syncthreads();
#pragma unroll
        for (int k = 0; k < 8; ++k) {
            const int idx = k * 256 + t;  // 2048 = 128 i x 16 c4
            const int i = idx >> 4, c4 = idx & 15;
            const float g = gl[i];
            const float4 s = ((const float4*)S)[(b * NN + i0 + i) * 16 + c4];
            tr[(c4 * 4 + 0) * 132 + i] = s.x * g;
            tr[(c4 * 4 + 1) * 132 + i] = s.y * g;
            tr[(c4 * 4 + 2) * 132 + i] = s.z * g;
            tr[(c4 * 4 + 3) * 132 + i] = s.w * g;
        }
        __syncthreads();
#pragma unroll
        for (int pass = 0; pass < 4; ++pass) {
            const int row = pass * 16 + (t >> 4);
            const int ln16 = t & 15;
            const float4 a = *(const float4*)&tr[row * 132 + ln16 * 8];
            const float4 c = *(const float4*)&tr[row * 132 + ln16 * 8 + 4];
            bf16x8 v;
            v[0] = f2bf(a.x); v[1] = f2bf(a.y); v[2] = f2bf(a.z); v[3] = f2bf(a.w);
            v[4] = f2bf(c.x); v[5] = f2bf(c.y); v[6] = f2bf(c.z); v[7] = f2bf(c.w);
            // 16 lanes x 16B = 256B contiguous per row chunk
            *(bf16x8*)(es_t + (size_t)(b * 64 + row) * NN + i0 + ln16 * 8) = v;
        }
    }
}

// ---------------------------------------------------------------------------
// Transfer: grid (N/JT, ISPLIT), 256 threads. MFMA phases as round 4.
// Epilogue: fp16 partials, 64B/thread coalesced stores (NO atomics).
// ---------------------------------------------------------------------------
__global__ __launch_bounds__(256, 4) void transfer_kernel(const short* __restrict__ P_bf,
                                                          const short* __restrict__ U_bf,
                                                          const short* __restrict__ es_t,
                                                          const float* __restrict__ bias_p,
                                                          unsigned short* __restrict__ part) {
    // T in MFMA-A fragment order: [jt*2+ks][lane][e(8 shorts)] = 8 KB
    __shared__ __align__(16) short TT[8 * 64 * 8];

    const int t = threadIdx.x;
    const int w = t >> 6;
    const int lane = t & 63;
    const int q = lane >> 4;
    const int ln = lane & 15;
    const int j0 = blockIdx.x * JT;
    const int i_base = blockIdx.y * ISPAN;
    const float nb = -bias_p[0] * LOG2E;  // exp term: exp2(s*-LOG2E + nb)

    // U B-fragments resident in registers for the whole kernel
    bf16x8 uf[4][2];
#pragma unroll
    for (int jt = 0; jt < 4; ++jt)
#pragma unroll
        for (int ks = 0; ks < 2; ++ks)
            uf[jt][ks] = *(const bf16x8*)(U_bf + (j0 + jt * 16 + ln) * EE + ks * 32 + q * 8);

    f32x4 acc[4][2];
#pragma unroll
    for (int jm = 0; jm < 4; ++jm)
#pragma unroll
        for (int c = 0; c < 2; ++c) acc[jm][c] = (f32x4){0.f, 0.f, 0.f, 0.f};
    const f32x4 zero = (f32x4){0.f, 0.f, 0.f, 0.f};

    // producer TT slot: i_local = 16w+4q+r -> ks=(w>>1), q'=(2w+(q>>1))&3, e0=(q&1)*4
    const int ks_w = w >> 1;
    const int qp = (2 * w + (q >> 1)) & 3;
    const int e0 = (q & 1) * 4;
    const int ttw_off = (ks_w * 64 + qp * 16 + ln) * 2 + (e0 >> 2);  // uint2 units

    for (int chunk = 0; chunk < ISPAN / IC; ++chunk) {
        const int i0 = i_base + chunk * IC;
        const bool diag = (i0 == j0);

        // issue global fragment loads early (L2-resident; hide latency over barrier)
        bf16x8 pf[2];
#pragma unroll
        for (int ks = 0; ks < 2; ++ks)
            pf[ks] = *(const bf16x8*)(P_bf + (i0 + w * 16 + ln) * EE + ks * 32 + q * 8);
        bf16x8 bfr[2][2];
#pragma unroll
        for (int c = 0; c < 2; ++c) {
            const int g = w * 2 + c;
            const short* er = es_t + (size_t)(((g >> 2) * 64) + (g & 3) * 16 + ln) * NN + i0;
#pragma unroll
            for (int ks = 0; ks < 2; ++ks)
                bfr[c][ks] = *(const bf16x8*)(er + ks * 32 + q * 8);
        }

        __syncthreads();  // TT from previous chunk fully consumed

        // ---- phase A: scores -> sigmoid -> T in A-fragment order ----
#pragma unroll
        for (int jt = 0; jt < 4; ++jt) {
            f32x4 s = __builtin_amdgcn_mfma_f32_16x16x32_bf16(pf[0], uf[jt][0], zero, 0, 0, 0);
            s = __builtin_amdgcn_mfma_f32_16x16x32_bf16(pf[1], uf[jt][1], s, 0, 0, 0);
            float T[4];
#pragma unroll
            for (int r = 0; r < 4; ++r)
                T[r] = __builtin_amdgcn_rcpf(
                    1.f + __builtin_amdgcn_exp2f(fmaf(s[r], -LOG2E, nb)));
            if (diag && jt == w) {  // 1 of 16 chunks per block
                const int rr = ln - 4 * q;
                if (rr >= 0 && rr < 4) T[rr] = 0.f;
            }
            uint2 pk;
            pk.x = pack_bf_trunc(T[0], T[1]);
            pk.y = pack_bf_trunc(T[2], T[3]);
            ((uint2*)TT)[jt * 256 + ttw_off] = pk;
        }
        __syncthreads();  // TT complete

        // ---- phase B: out[j][d] += T^T[j][i] * es[i][d] ----
#pragma unroll
        for (int jm = 0; jm < 4; ++jm) {
#pragma unroll
            for (int ks = 0; ks < 2; ++ks) {
                const bf16x8 af = *(const bf16x8*)(TT + ((jm * 2 + ks) * 64 + lane) * 8);
                acc[jm][0] = __builtin_amdgcn_mfma_f32_16x16x32_bf16(af, bfr[0][ks], acc[jm][0], 0, 0, 0);
                acc[jm][1] = __builtin_amdgcn_mfma_f32_16x16x32_bf16(af, bfr[1][ks], acc[jm][1], 0, 0, 0);
            }
        }
    }

    // epilogue: fp16 partials, thread-contiguous 64B slot, fully coalesced
    unsigned short* pb =
        part + ((size_t)(blockIdx.y * (NN / JT) + blockIdx.x) * 256 + t) * 32;
#pragma unroll
    for (int jm = 0; jm < 4; ++jm) {
        uint4 v;
        v.x = pk_f16(acc[jm][0][0], acc[jm][0][1]);
        v.y = pk_f16(acc[jm][0][2], acc[jm][0][3]);
        v.z = pk_f16(acc[jm][1][0], acc[jm][1][1]);
        v.w = pk_f16(acc[jm][1][2], acc[jm][1][3]);
        *(uint4*)(pb + jm * 8) = v;
    }
}

// ---------------------------------------------------------------------------
// Reduce: out[b][j][d] = state + sum_y partial_y. grid (128, 2) x 256.
// blockIdx.y selects jm pair {2s, 2s+1}; slot mapping mirrors transfer.
// ---------------------------------------------------------------------------
__global__ __launch_bounds__(256) void reduce_kernel(const unsigned short* __restrict__ part,
                                                     const float* __restrict__ S,
                                                     float* __restrict__ out) {
    const int t = threadIdx.x;
    const int jx = blockIdx.x;  // 0..127
    const int s = blockIdx.y;   // 0..1
    const int w = t >> 6, lane = t & 63, q = lane >> 4, ln = lane & 15;

    float acc[2][2][4];
#pragma unroll
    for (int jj = 0; jj < 2; ++jj)
#pragma unroll
        for (int c = 0; c < 2; ++c)
#pragma unroll
            for (int r = 0; r < 4; ++r) acc[jj][c][r] = 0.f;

#pragma unroll
    for (int y = 0; y < ISPLIT; ++y) {
        const unsigned short* pb = part + ((size_t)(y * (NN / JT) + jx) * 256 + t) * 32;
#pragma unroll
        for (int jj = 0; jj < 2; ++jj) {
            const int jm = s * 2 + jj;
            const uint4 v = *(const uint4*)(pb + jm * 8);
            acc[jj][0][0] += f16lo(v.x); acc[jj][0][1] += f16hi(v.x);
            acc[jj][0][2] += f16lo(v.y); acc[jj][0][3] += f16hi(v.y);
            acc[jj][1][0] += f16lo(v.z); acc[jj][1][1] += f16hi(v.z);
            acc[jj][1][2] += f16lo(v.w); acc[jj][1][3] += f16hi(v.w);
        }
    }
#pragma unroll
    for (int jj = 0; jj < 2; ++jj)
#pragma unroll
        for (int c = 0; c < 2; ++c) {
            const int g = w * 2 + c;
            const int bb = g >> 2, dt = g & 3;
            const int j = jx * 64 + (s * 2 + jj) * 16 + q * 4;
#pragma unroll
            for (int r = 0; r < 4; ++r) {
                const int idx = (bb * NN + j + r) * DD + dt * 16 + ln;
                out[idx] = S[idx] + acc[jj][c][r];
            }
        }
}

// ---------------------------------------------------------------------------
extern "C" void kernel_launch(void* const* d_in, const int* in_sizes, int n_in,
                              void* d_out, int out_size, void* d_ws, size_t ws_size,
                              hipStream_t stream) {
    const float* states = (const float*)d_in[0];  // [B,N,D]
    const float* prof   = (const float*)d_in[1];  // [B,N]
    const float* emb    = (const float*)d_in[2];  // [N,E]
    const float* W      = (const float*)d_in[3];  // [1,E,E]
    const float* bias   = (const float*)d_in[4];  // [1]
    float* out = (float*)d_out;

    short* P_bf = (short*)d_ws;                 // 1 MB
    short* U_bf = P_bf + NN * EE;               // 1 MB
    short* es_t = U_bf + NN * EE;               // 2 MB
    unsigned short* part = (unsigned short*)(es_t + (size_t)NB * 64 * NN);  // 16 MB

    prep_kernel<<<640, 256, 0, stream>>>(emb, W, states, prof, P_bf, U_bf, es_t);
    transfer_kernel<<<dim3(NN / JT, ISPLIT), 256, 0, stream>>>(P_bf, U_bf, es_t, bias, part);
    reduce_kernel<<<dim3(NN / JT, 2), 256, 0, stream>>>(part, states, out);
}

// Round 7
// 130.173 us; speedup vs baseline: 3.7915x; 1.0026x over previous
//
#include <hip/hip_runtime.h>
#include <math.h>

#define NN 8192
#define DD 64
#define EE 64
#define NB 2
#define THRESH 0.7f
#define JT 64
#define IC 64
#define ISPLIT 8
#define ISPAN (NN / ISPLIT)
#define LOG2E 1.4426950408889634f

typedef __attribute__((ext_vector_type(8))) short bf16x8;
typedef __attribute__((ext_vector_type(4))) float f32x4;
typedef __fp16 half2v __attribute__((ext_vector_type(2)));

static __device__ __forceinline__ short f2bf(float x) {  // RNE
    unsigned u = __float_as_uint(x);
    unsigned r = (u + 0x7fffu + ((u >> 16) & 1u)) >> 16;
    return (short)r;
}
static __device__ __forceinline__ unsigned pack_bf_trunc(float lo, float hi) {
    return __builtin_amdgcn_perm(__float_as_uint(hi), __float_as_uint(lo), 0x07060302u);
}
static __device__ __forceinline__ unsigned pk_f16(float a, float b) {
    half2v h = __builtin_amdgcn_cvt_pkrtz(a, b);
    return __builtin_bit_cast(unsigned, h);
}
static __device__ __forceinline__ float f16lo(unsigned u) {
    half2v h = __builtin_bit_cast(half2v, u);
    return (float)h[0];
}
static __device__ __forceinline__ float f16hi(unsigned u) {
    half2v h = __builtin_bit_cast(half2v, u);
    return (float)h[1];
}

// ---------------------------------------------------------------------------
// Prep: blocks [0,512): P = U@W -> bf16, U -> bf16.
//       blocks [512,640): es_t[b*64+d][i] transpose, contiguous 256B stores.
// ---------------------------------------------------------------------------
__global__ __launch_bounds__(256) void prep_kernel(const float* __restrict__ U,
                                                   const float* __restrict__ W,
                                                   const float* __restrict__ S,
                                                   const float* __restrict__ prof,
                                                   short* __restrict__ P_bf,
                                                   short* __restrict__ U_bf,
                                                   short* __restrict__ es_t) {
    __shared__ float smem[64 * 132 + 128];  // 34.3 KB (manual union)
    const int t = threadIdx.x;

    if (blockIdx.x < 512) {
        float* Wl = smem;
        float* Ul = smem + 4096;
        const int r0 = blockIdx.x * 16;
#pragma unroll
        for (int k = 0; k < 4; ++k)
            ((float4*)Wl)[k * 256 + t] = ((const float4*)W)[k * 256 + t];
        ((float4*)Ul)[t] = ((const float4*)U)[r0 * 16 + t];
        __syncthreads();
        const int row = t >> 4;
        const int fq = t & 15;
        const float* ur = Ul + row * EE;
        float4 acc = {0.f, 0.f, 0.f, 0.f};
#pragma unroll
        for (int e = 0; e < EE; ++e) {
            const float4 w4 = ((const float4*)Wl)[e * 16 + fq];
            const float u = ur[e];
            acc.x += u * w4.x; acc.y += u * w4.y;
            acc.z += u * w4.z; acc.w += u * w4.w;
        }
        short4 pv = {f2bf(acc.x), f2bf(acc.y), f2bf(acc.z), f2bf(acc.w)};
        *(short4*)(P_bf + (r0 + row) * EE + fq * 4) = pv;
        const float4 uv = ((const float4*)ur)[fq];
        short4 ub = {f2bf(uv.x), f2bf(uv.y), f2bf(uv.z), f2bf(uv.w)};
        *(short4*)(U_bf + (r0 + row) * EE + fq * 4) = ub;
    } else {
        float* tr = smem;           // [64][132]
        float* gl = smem + 8448;    // [128]
        const int bi = blockIdx.x - 512;  // 0..127
        const int b = bi >> 6;
        const int i0 = (bi & 63) * 128;
        if (t < 128) gl[t] = fmaxf(prof[b * NN + i0 + t] - THRESH, 0.f);
        __syncthreads();
#pragma unroll
        for (int k = 0; k < 8; ++k) {
            const int idx = k * 256 + t;  // 2048 = 128 i x 16 c4
            const int i = idx >> 4, c4 = idx & 15;
            const float g = gl[i];
            const float4 s = ((const float4*)S)[(b * NN + i0 + i) * 16 + c4];
            tr[(c4 * 4 + 0) * 132 + i] = s.x * g;
            tr[(c4 * 4 + 1) * 132 + i] = s.y * g;
            tr[(c4 * 4 + 2) * 132 + i] = s.z * g;
            tr[(c4 * 4 + 3) * 132 + i] = s.w * g;
        }
        __syncthreads();
#pragma unroll
        for (int pass = 0; pass < 4; ++pass) {
            const int row = pass * 16 + (t >> 4);
            const int ln16 = t & 15;
            const float4 a = *(const float4*)&tr[row * 132 + ln16 * 8];
            const float4 c = *(const float4*)&tr[row * 132 + ln16 * 8 + 4];
            bf16x8 v;
            v[0] = f2bf(a.x); v[1] = f2bf(a.y); v[2] = f2bf(a.z); v[3] = f2bf(a.w);
            v[4] = f2bf(c.x); v[5] = f2bf(c.y); v[6] = f2bf(c.z); v[7] = f2bf(c.w);
            *(bf16x8*)(es_t + (size_t)(b * 64 + row) * NN + i0 + ln16 * 8) = v;
        }
    }
}

// ---------------------------------------------------------------------------
// Transfer: grid (N/JT, ISPLIT), 256 threads. Software-pipelined:
//   iter c: phaseA(c+1) -> TT[b^1]  ||  phaseB(c) <- TT[b]; ONE barrier/chunk.
// ---------------------------------------------------------------------------
__global__ __launch_bounds__(256, 3) void transfer_kernel(const short* __restrict__ P_bf,
                                                          const short* __restrict__ U_bf,
                                                          const short* __restrict__ es_t,
                                                          const float* __restrict__ bias_p,
                                                          unsigned short* __restrict__ part) {
    // T in MFMA-A fragment order, double-buffered: [buf][tile][lane][8 shorts]
    __shared__ __align__(16) short TT[2][8 * 64 * 8];  // 16 KB

    const int t = threadIdx.x;
    const int w = t >> 6;
    const int lane = t & 63;
    const int q = lane >> 4;
    const int ln = lane & 15;
    const int j0 = blockIdx.x * JT;
    const int i_base = blockIdx.y * ISPAN;
    const float nb = -bias_p[0] * LOG2E;

    // U B-fragments resident for the whole kernel
    bf16x8 uf[4][2];
#pragma unroll
    for (int jt = 0; jt < 4; ++jt)
#pragma unroll
        for (int ks = 0; ks < 2; ++ks)
            uf[jt][ks] = *(const bf16x8*)(U_bf + (j0 + jt * 16 + ln) * EE + ks * 32 + q * 8);

    f32x4 acc[4][2];
#pragma unroll
    for (int jm = 0; jm < 4; ++jm)
#pragma unroll
        for (int c = 0; c < 2; ++c) acc[jm][c] = (f32x4){0.f, 0.f, 0.f, 0.f};
    const f32x4 zero = (f32x4){0.f, 0.f, 0.f, 0.f};

    // producer TT slot: i_local=16w+4q+r -> ks=(w>>1), q'=(2w+(q>>1))&3, half=(q&1)
    const int ks_w = w >> 1;
    const int qp = (2 * w + (q >> 1)) & 3;
    const int ttw_off = (ks_w * 64 + qp * 16 + ln) * 2 + (q & 1);  // uint2 units

    auto load_p = [&](int cc, bf16x8* pf) {
        const int i0 = i_base + cc * IC;
#pragma unroll
        for (int ks = 0; ks < 2; ++ks)
            pf[ks] = *(const bf16x8*)(P_bf + (i0 + w * 16 + ln) * EE + ks * 32 + q * 8);
    };
    auto load_es = [&](int cc, bf16x8 (*bfr)[2]) {
        const int i0 = i_base + cc * IC;
#pragma unroll
        for (int c = 0; c < 2; ++c) {
            const int g = w * 2 + c;
            const short* er = es_t + (size_t)((g >> 2) * 64 + (g & 3) * 16 + ln) * NN + i0;
#pragma unroll
            for (int ks = 0; ks < 2; ++ks)
                bfr[c][ks] = *(const bf16x8*)(er + ks * 32 + q * 8);
        }
    };
    auto phase_a = [&](int cc, const bf16x8* pf, short* tt) {
        const int i0 = i_base + cc * IC;
        const bool dg = (i0 == j0);
#pragma unroll
        for (int jt = 0; jt < 4; ++jt) {
            f32x4 s = __builtin_amdgcn_mfma_f32_16x16x32_bf16(pf[0], uf[jt][0], zero, 0, 0, 0);
            s = __builtin_amdgcn_mfma_f32_16x16x32_bf16(pf[1], uf[jt][1], s, 0, 0, 0);
            float T[4];
#pragma unroll
            for (int r = 0; r < 4; ++r)
                T[r] = __builtin_amdgcn_rcpf(
                    1.f + __builtin_amdgcn_exp2f(fmaf(s[r], -LOG2E, nb)));
            if (dg && jt == w) {  // 1 of 16 chunks per block
                const int rr = ln - 4 * q;
                if (rr >= 0 && rr < 4) T[rr] = 0.f;
            }
            uint2 pk;
            pk.x = pack_bf_trunc(T[0], T[1]);
            pk.y = pack_bf_trunc(T[2], T[3]);
            ((uint2*)tt)[jt * 256 + ttw_off] = pk;
        }
    };
    auto phase_b = [&](const bf16x8 (*bfr)[2], const short* tt) {
#pragma unroll
        for (int jm = 0; jm < 4; ++jm)
#pragma unroll
            for (int ks = 0; ks < 2; ++ks) {
                const bf16x8 af = *(const bf16x8*)(tt + ((jm * 2 + ks) * 64 + lane) * 8);
                acc[jm][0] = __builtin_amdgcn_mfma_f32_16x16x32_bf16(af, bfr[0][ks], acc[jm][0], 0, 0, 0);
                acc[jm][1] = __builtin_amdgcn_mfma_f32_16x16x32_bf16(af, bfr[1][ks], acc[jm][1], 0, 0, 0);
            }
    };

    // prologue
    bf16x8 pfA[2], pfB[2], bfA[2][2], bfB[2][2];
    load_p(0, pfA);
    load_es(0, bfA);
    load_p(1, pfB);
    phase_a(0, pfA, TT[0]);
    __syncthreads();  // TT[0] ready

    const int NCH = ISPAN / IC;  // 16
#pragma unroll
    for (int c = 0; c < NCH; c += 2) {
        // even iter: A(c+1)->TT1 || B(c)<-TT0
        if (c + 1 < NCH) load_es(c + 1, bfB);
        if (c + 2 < NCH) load_p(c + 2, pfA);
        if (c + 1 < NCH) phase_a(c + 1, pfB, TT[1]);
        phase_b(bfA, TT[0]);
        __syncthreads();
        // odd iter: A(c+2)->TT0 || B(c+1)<-TT1
        if (c + 2 < NCH) load_es(c + 2, bfA);
        if (c + 3 < NCH) load_p(c + 3, pfB);
        if (c + 2 < NCH) phase_a(c + 2, pfA, TT[0]);
        if (c + 1 < NCH) phase_b(bfB, TT[1]);
        __syncthreads();
    }

    // epilogue: fp16 partials in [jm-plane][thread] layout (coalesced both ways)
    unsigned short* pb = part + (size_t)(blockIdx.y * (NN / JT) + blockIdx.x) * 8192;
#pragma unroll
    for (int jm = 0; jm < 4; ++jm) {
        uint4 v;
        v.x = pk_f16(acc[jm][0][0], acc[jm][0][1]);
        v.y = pk_f16(acc[jm][0][2], acc[jm][0][3]);
        v.z = pk_f16(acc[jm][1][0], acc[jm][1][1]);
        v.w = pk_f16(acc[jm][1][2], acc[jm][1][3]);
        *(uint4*)(pb + jm * 2048 + t * 8) = v;
    }
}

// ---------------------------------------------------------------------------
// Reduce: out[b][j][d] = state + sum_y partial_y. grid (128, 2) x 256.
// ---------------------------------------------------------------------------
__global__ __launch_bounds__(256) void reduce_kernel(const unsigned short* __restrict__ part,
                                                     const float* __restrict__ S,
                                                     float* __restrict__ out) {
    const int t = threadIdx.x;
    const int jx = blockIdx.x;  // 0..127
    const int s = blockIdx.y;   // 0..1
    const int w = t >> 6, lane = t & 63, q = lane >> 4, ln = lane & 15;

    float acc[2][2][4];
#pragma unroll
    for (int jj = 0; jj < 2; ++jj)
#pragma unroll
        for (int c = 0; c < 2; ++c)
#pragma unroll
            for (int r = 0; r < 4; ++r) acc[jj][c][r] = 0.f;

#pragma unroll
    for (int y = 0; y < ISPLIT; ++y) {
        const unsigned short* pb = part + (size_t)(y * (NN / JT) + jx) * 8192;
#pragma unroll
        for (int jj = 0; jj < 2; ++jj) {
            const int jm = s * 2 + jj;
            const uint4 v = *(const uint4*)(pb + jm * 2048 + t * 8);  // coalesced
            acc[jj][0][0] += f16lo(v.x); acc[jj][0][1] += f16hi(v.x);
            acc[jj][0][2] += f16lo(v.y); acc[jj][0][3] += f16hi(v.y);
            acc[jj][1][0] += f16lo(v.z); acc[jj][1][1] += f16hi(v.z);
            acc[jj][1][2] += f16lo(v.w); acc[jj][1][3] += f16hi(v.w);
        }
    }
#pragma unroll
    for (int jj = 0; jj < 2; ++jj)
#pragma unroll
        for (int c = 0; c < 2; ++c) {
            const int g = w * 2 + c;
            const int bb = g >> 2, dt = g & 3;
            const int j = jx * 64 + (s * 2 + jj) * 16 + q * 4;
#pragma unroll
            for (int r = 0; r < 4; ++r) {
                const int idx = (bb * NN + j + r) * DD + dt * 16 + ln;
                out[idx] = S[idx] + acc[jj][c][r];
            }
        }
}

// ---------------------------------------------------------------------------
extern "C" void kernel_launch(void* const* d_in, const int* in_sizes, int n_in,
                              void* d_out, int out_size, void* d_ws, size_t ws_size,
                              hipStream_t stream) {
    const float* states = (const float*)d_in[0];  // [B,N,D]
    const float* prof   = (const float*)d_in[1];  // [B,N]
    const float* emb    = (const float*)d_in[2];  // [N,E]
    const float* W      = (const float*)d_in[3];  // [1,E,E]
    const float* bias   = (const float*)d_in[4];  // [1]
    float* out = (float*)d_out;

    short* P_bf = (short*)d_ws;                 // 1 MB
    short* U_bf = P_bf + NN * EE;               // 1 MB
    short* es_t = U_bf + NN * EE;               // 2 MB
    unsigned short* part = (unsigned short*)(es_t + (size_t)NB * 64 * NN);  // 16 MB

    prep_kernel<<<640, 256, 0, stream>>>(emb, W, states, prof, P_bf, U_bf, es_t);
    transfer_kernel<<<dim3(NN / JT, ISPLIT), 256, 0, stream>>>(P_bf, U_bf, es_t, bias, part);
    reduce_kernel<<<dim3(NN / JT, 2), 256, 0, stream>>>(part, states, out);
}